// Round 1
// baseline (551.086 us; speedup 1.0000x reference)
//
#include <hip/hip_runtime.h>

// Problem: B=32, S=128, V=32000.
// loss = -sum_{b,s} prob[b,s,target[b,s]] * reward[b]
// Only 4096 gathered floats are live out of the 524MB prob tensor -> pure
// latency-bound gather + reduction. Never scan prob.

constexpr int B = 32;
constexpr int S = 128;
constexpr int V = 32000;
constexpr int N = B * S; // 4096

// 16 blocks x 256 threads; one (b,s) element per thread.
__global__ __launch_bounds__(256) void gather_partial(
    const float* __restrict__ prob,
    const int*   __restrict__ target,
    const float* __restrict__ reward,
    float*       __restrict__ partial)
{
    const int i = blockIdx.x * 256 + threadIdx.x; // i in [0, 4096)
    const int t = target[i];
    // i >> 7 == i / S gives the batch index b for the reward broadcast.
    float v = prob[(size_t)i * V + (size_t)t] * reward[i >> 7];

    // wave(64)-wide reduction
    #pragma unroll
    for (int off = 32; off; off >>= 1)
        v += __shfl_down(v, off, 64);

    __shared__ float s[4];
    if ((threadIdx.x & 63) == 0) s[threadIdx.x >> 6] = v;
    __syncthreads();
    if (threadIdx.x == 0)
        partial[blockIdx.x] = s[0] + s[1] + s[2] + s[3];
}

// Reduce the 16 block partials, negate, write scalar out.
__global__ __launch_bounds__(64) void final_reduce(
    const float* __restrict__ partial,
    float*       __restrict__ out)
{
    float v = (threadIdx.x < 16) ? partial[threadIdx.x] : 0.0f;
    #pragma unroll
    for (int off = 8; off; off >>= 1)
        v += __shfl_down(v, off, 64);
    if (threadIdx.x == 0) out[0] = -v;
}

extern "C" void kernel_launch(void* const* d_in, const int* in_sizes, int n_in,
                              void* d_out, int out_size, void* d_ws, size_t ws_size,
                              hipStream_t stream)
{
    const float* prob   = (const float*)d_in[0];
    const int*   target = (const int*)  d_in[1]; // harness passes integers as int32
    const float* reward = (const float*)d_in[2];
    float*       out    = (float*)d_out;
    float*       partial = (float*)d_ws; // 16 floats of scratch

    gather_partial<<<16, 256, 0, stream>>>(prob, target, reward, partial);
    final_reduce<<<1, 64, 0, stream>>>(partial, out);
}